// Round 13
// baseline (363.832 us; speedup 1.0000x reference)
//
#include <hip/hip_runtime.h>

// ConvLSTM2D x2, 2-step temporal blocking, 9 launches, LDS-resident weights.
// Launch j: L1 computes t=2j,2j+1; L2 computes t=2j-2,2j-1 (prev-launch deps).
// Block = 2 own rows, 1024 thr (16 waves). Weights re-packed src-major; block
// stages one 72 KB src-slice in LDS at a time (L2 weight traffic 1.2GB->74MB):
//   P1 stage tiles + W<-src0 | P2 x-side MFMAs for BOTH steps (shared B reads)
//   P3 W<-src1, zero tHA     | P4 h-side step A + epilogue (c in owner regs)
//   P5 h-side step B (src1 still resident) + epilogue.
// tXB and tHA share LDS (disjoint lifetimes). Tile stride 34 (<=2-way banks).

typedef __bf16 bf16x8 __attribute__((ext_vector_type(8)));
typedef float f32x4 __attribute__((ext_vector_type(4)));

#define WPK_ELEMS 73728   // per layer
#define SRC_SLICE 36864   // elems per (layer,src) slice = 72 KB
#define PLANE 524288      // 4*64*64*32 elems per plane
#define TS 34             // LDS tile channel stride

__device__ __forceinline__ float fsigmoid(float z) {
    return 1.0f / (1.0f + __expf(-z));
}
__device__ __forceinline__ float ftanh(float z) {
    z = fminf(15.0f, fmaxf(-15.0f, z));
    float e = __expf(2.0f * z);
    return (e - 1.0f) / (e + 1.0f);
}

// Pack wk/wr (3,3,32,128) fp32 -> wpk[layer][src][tap][nt][lane][j2] bf16.
// nt = (fhalf<<2)|gate; col n = gate*32 + fhalf*16 + (lane&15);
// k-in-chunk s = (lane>>4)*8 + j2.
__global__ __launch_bounds__(256) void pack_weights(
    const float* __restrict__ wk1, const float* __restrict__ wr1,
    const float* __restrict__ wk2, const float* __restrict__ wr2,
    __bf16* __restrict__ wpk)
{
    int i = blockIdx.x * 256 + threadIdx.x;
    if (i >= 2 * WPK_ELEMS) return;
    int layer = i / WPK_ELEMS;
    int r = i - layer * WPK_ELEMS;
    int j2 = r & 7;
    int L  = (r >> 3) & 63;
    int nt = (r >> 9) & 7;
    int st = r >> 12;             // 0..17 = src*9 + tap
    int src = st / 9, tap = st - src * 9;
    int s = ((L >> 4) << 3) + j2;
    int gate = nt & 3;
    int f = ((nt >> 2) << 4) + (L & 15);
    int n = (gate << 5) + f;
    const float* w = layer ? (src ? wr2 : wk2) : (src ? wr1 : wk1);
    wpk[i] = (__bf16)w[(tap * 32 + s) * 128 + n];
}

__device__ __forceinline__ bf16x8 cvt8(const float* p) {
    const float4 f0 = *(const float4*)p;
    const float4 f1 = *(const float4*)(p + 4);
    bf16x8 v;
    v[0] = (__bf16)f0.x; v[1] = (__bf16)f0.y;
    v[2] = (__bf16)f0.z; v[3] = (__bf16)f0.w;
    v[4] = (__bf16)f1.x; v[5] = (__bf16)f1.y;
    v[6] = (__bf16)f1.z; v[7] = (__bf16)f1.w;
    return v;
}

#define MFMA8(A0, A1, WP, ACC)                                                            \
    ACC[0][0] = __builtin_amdgcn_mfma_f32_16x16x32_bf16(A0, WP[0],   ACC[0][0], 0, 0, 0); \
    ACC[0][1] = __builtin_amdgcn_mfma_f32_16x16x32_bf16(A0, WP[64],  ACC[0][1], 0, 0, 0); \
    ACC[0][2] = __builtin_amdgcn_mfma_f32_16x16x32_bf16(A0, WP[128], ACC[0][2], 0, 0, 0); \
    ACC[0][3] = __builtin_amdgcn_mfma_f32_16x16x32_bf16(A0, WP[192], ACC[0][3], 0, 0, 0); \
    ACC[1][0] = __builtin_amdgcn_mfma_f32_16x16x32_bf16(A1, WP[0],   ACC[1][0], 0, 0, 0); \
    ACC[1][1] = __builtin_amdgcn_mfma_f32_16x16x32_bf16(A1, WP[64],  ACC[1][1], 0, 0, 0); \
    ACC[1][2] = __builtin_amdgcn_mfma_f32_16x16x32_bf16(A1, WP[128], ACC[1][2], 0, 0, 0); \
    ACC[1][3] = __builtin_amdgcn_mfma_f32_16x16x32_bf16(A1, WP[192], ACC[1][3], 0, 0, 0);

__global__ __launch_bounds__(1024, 1) void clstm_wlds(
    const float* __restrict__ x,
    const __bf16* __restrict__ wpk1, const __bf16* __restrict__ wpk2,
    const float* __restrict__ bias1, const float* __restrict__ bias2,
    __bf16* __restrict__ h1buf,       // 4 planes, t%4
    __bf16* __restrict__ h2buf,       // 2 parity planes
    float* __restrict__ c1,           // 2 parity planes
    float* __restrict__ c2,
    float* __restrict__ out, int j)
{
    __shared__ __bf16 Wl[SRC_SLICE];        // 72 KB current-src weight slice
    __shared__ __bf16 tXA[6 * 66 * TS];     // step-A input src rows y0-2..y0+3
    __shared__ __bf16 tRA[6 * 66 * TS];     // step-A recurrent src (h@T0-1)
    __shared__ __bf16 tHB[4 * 66 * TS];     // P1-2: x@T0+1 tile; P3+: h@T0 (tHA)

    const int blk = blockIdx.x;
    const int k = blk >> 3;
    const int layer = k >> 4;
    if (layer ? (j < 1) : (j > 7)) return;
    const int grp = (blk & 7) * 16 + (k & 15);   // XCD-contiguous rows
    const int T0 = layer ? (2 * j - 2) : (2 * j);
    const int R = grp << 1;
    const int b = R >> 6, y0 = R & 63;

    const int tid = threadIdx.x;
    const int wid = tid >> 6, L = tid & 63;
    const int c = L & 15, q = L >> 4, q8 = q * 8;
    const int wr = wid >> 2;          // window row 0..3 -> y0-1..y0+2
    const int fh = (wid >> 1) & 1;
    const int mp = wid & 1;
    const int f = fh * 16 + c;
    const bool owner = (wr == 1 || wr == 2);
    const int o = wr - 1;             // owner's step-B row index (0..1)

    const __bf16* wpkL = layer ? wpk2 : wpk1;
    const float* bias = layer ? bias2 : bias1;
    float bv[4];
    #pragma unroll
    for (int g = 0; g < 4; ++g) bv[g] = bias[g * 32 + f];

    const float*  xA  = x + (size_t)(b * 16 + T0) * 131072;
    const float*  xB  = xA + 131072;
    const __bf16* h1A = h1buf + (size_t)(T0 & 3) * PLANE;
    const __bf16* h1B = h1buf + (size_t)((T0 + 1) & 3) * PLANE;
    const __bf16* hRA = layer ? (h2buf + (size_t)(((T0 - 1) >> 1) & 1) * PLANE)
                              : (h1buf + (size_t)((T0 - 1) & 3) * PLANE);

    // ================= P1: stage W<-src0, tXA (+tRA), tHB<-x-side@T0+1 ======
    for (int i = tid; i < SRC_SLICE / 8; i += 1024)
        *(bf16x8*)(Wl + i * 8) = *(const bf16x8*)(wpkL + (size_t)i * 8);

    const int n1 = T0 ? 3168 : 1584;
    for (int i = tid; i < n1; i += 1024) {
        const int tile = (i >= 1584);
        const int r2 = i - tile * 1584;
        const int g = r2 & 3;
        const int rc = r2 >> 2;
        const int cc = rc % 66;
        const int row = rc / 66;
        const int yy = y0 - 2 + row;
        const int xc = cc - 1;
        bf16x8 v = {};
        if ((unsigned)yy < 64u && (unsigned)xc < 64u) {
            if (!layer && !tile) {
                v = cvt8(xA + ((size_t)yy * 64 + xc) * 32 + g * 8);
            } else {
                const __bf16* s = tile ? hRA : h1A;
                v = *(const bf16x8*)(s + (((size_t)(b * 64 + yy)) * 64 + xc) * 32 + g * 8);
            }
        }
        *(bf16x8*)((tile ? tRA : tXA) + (row * 66 + cc) * TS + g * 8) = v;
    }
    for (int i = tid; i < 1056; i += 1024) {
        const int g = i & 3;
        const int rc = i >> 2;
        const int cc = rc % 66;
        const int row = rc / 66;
        const int yy = y0 - 1 + row;
        const int xc = cc - 1;
        bf16x8 v = {};
        if ((unsigned)yy < 64u && (unsigned)xc < 64u) {
            if (!layer) v = cvt8(xB + ((size_t)yy * 64 + xc) * 32 + g * 8);
            else        v = *(const bf16x8*)(h1B + (((size_t)(b * 64 + yy)) * 64 + xc) * 32 + g * 8);
        }
        *(bf16x8*)(tHB + (row * 66 + cc) * TS + g * 8) = v;
    }
    __syncthreads();

    // ================= P2: x-side MFMAs for BOTH steps (shared B reads) =====
    f32x4 accA[2][4], accB[2][4];
    #pragma unroll
    for (int m2 = 0; m2 < 2; ++m2)
        #pragma unroll
        for (int g = 0; g < 4; ++g) {
            accA[m2][g] = (f32x4){bv[g], bv[g], bv[g], bv[g]};
            accB[m2][g] = (f32x4){bv[g], bv[g], bv[g], bv[g]};
        }

    #pragma unroll
    for (int tap = 0; tap < 9; ++tap) {
        const int dyk = tap / 3, dxk = tap - dyk * 3;
        const bf16x8* wl = (const bf16x8*)Wl + (size_t)(tap * 8 + fh * 4) * 64 + L;
        const int lbA = ((wr + dyk) * 66 + mp * 32 + c + dxk) * TS + q8;
        const bf16x8 a0 = *(const bf16x8*)(tXA + lbA);
        const bf16x8 a1 = *(const bf16x8*)(tXA + lbA + 16 * TS);
        MFMA8(a0, a1, wl, accA);
        if (owner) {
            const int lbB = ((o + dyk) * 66 + mp * 32 + c + dxk) * TS + q8;
            const bf16x8 b0 = *(const bf16x8*)(tHB + lbB);
            const bf16x8 b1 = *(const bf16x8*)(tHB + lbB + 16 * TS);
            MFMA8(b0, b1, wl, accB);
        }
    }
    __syncthreads();

    // ================= P3: W<-src1, zero tHB (becomes tHA) ==================
    for (int i = tid; i < SRC_SLICE / 8; i += 1024)
        *(bf16x8*)(Wl + i * 8) = *(const bf16x8*)(wpkL + (size_t)SRC_SLICE + (size_t)i * 8);
    for (int i = tid; i < 1122; i += 1024)
        *(bf16x8*)(tHB + i * 8) = (bf16x8){};
    __syncthreads();

    // ================= P4: h-side step A + epilogue A =======================
    const int ra = y0 - 1 + wr;
    const bool rv = ((unsigned)ra < 64u);
    if (T0 > 0 && rv) {
        #pragma unroll
        for (int tap = 0; tap < 9; ++tap) {
            const int dyk = tap / 3, dxk = tap - dyk * 3;
            const bf16x8* wl = (const bf16x8*)Wl + (size_t)(tap * 8 + fh * 4) * 64 + L;
            const int lbA = ((wr + dyk) * 66 + mp * 32 + c + dxk) * TS + q8;
            const bf16x8 h0 = *(const bf16x8*)(tRA + lbA);
            const bf16x8 h1v = *(const bf16x8*)(tRA + lbA + 16 * TS);
            MFMA8(h0, h1v, wl, accA);
        }
    }
    float cnv[2][4];
    if (rv) {
        const float* crd = (layer ? c2 : c1) + (size_t)(((T0 - 1) >> 1) & 1) * PLANE;
        const size_t rowA = (size_t)(b * 64 + ra) * 2048;
        #pragma unroll
        for (int m2 = 0; m2 < 2; ++m2) {
            #pragma unroll
            for (int r = 0; r < 4; ++r) {
                const int px = mp * 32 + m2 * 16 + q * 4 + r;
                const float ig = fsigmoid(accA[m2][0][r]);
                const float fg = fsigmoid(accA[m2][1][r]);
                const float gg = ftanh(accA[m2][2][r]);
                const float og = fsigmoid(accA[m2][3][r]);
                const float cold = T0 ? crd[rowA + (size_t)px * 32 + f] : 0.0f;
                const float cn = (T0 ? fg * cold : 0.0f) + ig * gg;
                const float hv = og * ftanh(cn);
                cnv[m2][r] = cn;
                tHB[(wr * 66 + px + 1) * TS + f] = (__bf16)hv;
                if (owner) {
                    if (layer)
                        out[((size_t)(b * 16 + T0) * 4096 + (size_t)ra * 64 + px) * 32 + f] = hv;
                    else
                        h1buf[(size_t)(T0 & 3) * PLANE + rowA + (size_t)px * 32 + f] = (__bf16)hv;
                }
            }
        }
    }
    __syncthreads();

    // ================= P5: h-side step B + epilogue B (owners) ==============
    if (owner) {
        #pragma unroll
        for (int tap = 0; tap < 9; ++tap) {
            const int dyk = tap / 3, dxk = tap - dyk * 3;
            const bf16x8* wl = (const bf16x8*)Wl + (size_t)(tap * 8 + fh * 4) * 64 + L;
            const int lbB = ((o + dyk) * 66 + mp * 32 + c + dxk) * TS + q8;
            const bf16x8 h0 = *(const bf16x8*)(tHB + lbB);
            const bf16x8 h1v = *(const bf16x8*)(tHB + lbB + 16 * TS);
            MFMA8(h0, h1v, wl, accB);
        }
        const int rb = y0 + o;
        float* cwr = (layer ? c2 : c1) + (size_t)(((T0 + 1) >> 1) & 1) * PLANE;
        __bf16* h2w = h2buf + (size_t)(((T0 + 1) >> 1) & 1) * PLANE;
        const size_t rowB = (size_t)(b * 64 + rb) * 2048;
        #pragma unroll
        for (int m2 = 0; m2 < 2; ++m2) {
            #pragma unroll
            for (int r = 0; r < 4; ++r) {
                const int px = mp * 32 + m2 * 16 + q * 4 + r;
                const float ig = fsigmoid(accB[m2][0][r]);
                const float fg = fsigmoid(accB[m2][1][r]);
                const float gg = ftanh(accB[m2][2][r]);
                const float og = fsigmoid(accB[m2][3][r]);
                const float cn = fg * cnv[m2][r] + ig * gg;
                const float hv = og * ftanh(cn);
                cwr[rowB + (size_t)px * 32 + f] = cn;
                if (layer) {
                    out[((size_t)(b * 16 + T0 + 1) * 4096 + (size_t)rb * 64 + px) * 32 + f] = hv;
                    h2w[rowB + (size_t)px * 32 + f] = (__bf16)hv;
                } else {
                    h1buf[(size_t)((T0 + 1) & 3) * PLANE + rowB + (size_t)px * 32 + f] = (__bf16)hv;
                }
            }
        }
    }
}

extern "C" void kernel_launch(void* const* d_in, const int* in_sizes, int n_in,
                              void* d_out, int out_size, void* d_ws, size_t ws_size,
                              hipStream_t stream)
{
    const float* x   = (const float*)d_in[0];
    const float* k1  = (const float*)d_in[1];
    const float* rk1 = (const float*)d_in[2];
    const float* b1  = (const float*)d_in[3];
    const float* k2  = (const float*)d_in[4];
    const float* rk2 = (const float*)d_in[5];
    const float* b2  = (const float*)d_in[6];
    float* out = (float*)d_out;

    __bf16* wpk1  = (__bf16*)d_ws;
    __bf16* wpk2  = wpk1 + WPK_ELEMS;
    __bf16* h1buf = wpk2 + WPK_ELEMS;             // 4 planes bf16
    __bf16* h2buf = h1buf + 4 * (size_t)PLANE;    // 2 planes bf16
    float*  c1    = (float*)(h2buf + 2 * (size_t)PLANE);  // 2 planes fp32
    float*  c2    = c1 + 2 * (size_t)PLANE;

    pack_weights<<<(2 * WPK_ELEMS + 255) / 256, 256, 0, stream>>>(k1, rk1, k2, rk2, wpk1);

    for (int j = 0; j <= 8; ++j) {
        clstm_wlds<<<512, 1024, 0, stream>>>(
            x, wpk1, wpk2, b1, b2, h1buf, h2buf, c1, c2, out, j);
    }
}

// Round 14
// 344.756 us; speedup vs baseline: 1.0553x; 1.0553x over previous
//
#include <hip/hip_runtime.h>

// ConvLSTM2D x2, 2-step temporal blocking, 9 launches, 2 blocks/CU overlap.
// Launch j: L1 computes t=2j,2j+1; L2 computes t=2j-2,2j-1 (prev-launch deps).
// 512 blocks x 512 thr (8 waves); block owns ONE row (layer,b,y0).
// Step A computes 3 window rows (y0-1..y0+1, 2 redundant) -> step B (own row)
// needs no cross-block sync. Waves: 0-5 = stepA units (row x mp, both fh);
// 6-7 = stepB (x-side in P2 overlapped, h-side in P3 from tHA). 2 barriers.
// LDS 80.0 KB -> 2 blocks/CU (32 waves). Weights streamed from L2/L1 per tap.

typedef __bf16 bf16x8 __attribute__((ext_vector_type(8)));
typedef float f32x4 __attribute__((ext_vector_type(4)));

#define WPK_ELEMS 73728   // per layer: 18 kchunks * 8 ntiles * 64 lanes * 8
#define PLANE 524288      // 4*64*64*32 elems per plane
#define TS 34             // LDS tile channel stride

__device__ __forceinline__ float fsigmoid(float z) {
    return 1.0f / (1.0f + __expf(-z));
}
__device__ __forceinline__ float ftanh(float z) {
    z = fminf(15.0f, fmaxf(-15.0f, z));
    float e = __expf(2.0f * z);
    return (e - 1.0f) / (e + 1.0f);
}

// Pack wk/wr (3,3,32,128) fp32 -> wpk[layer][tap*2+src][nt][lane][j2] bf16.
// col n' = nt*16 + (lane&15): gate = nt&3, f = (nt>>2)*16 + (lane&15).
__global__ __launch_bounds__(256) void pack_weights(
    const float* __restrict__ wk1, const float* __restrict__ wr1,
    const float* __restrict__ wk2, const float* __restrict__ wr2,
    __bf16* __restrict__ wpk)
{
    int i = blockIdx.x * 256 + threadIdx.x;
    if (i >= 2 * WPK_ELEMS) return;
    int layer = i / WPK_ELEMS;
    int r = i - layer * WPK_ELEMS;
    int j2 = r & 7;
    int L  = (r >> 3) & 63;
    int nt = (r >> 9) & 7;
    int cix = r >> 12;            // 0..17 = tap*2 + src
    int tap = cix >> 1, src = cix & 1;
    int s = ((L >> 4) << 3) + j2;
    int gate = nt & 3;
    int f = ((nt >> 2) << 4) + (L & 15);
    int n = (gate << 5) + f;
    const float* w = layer ? (src ? wr2 : wk2) : (src ? wr1 : wk1);
    wpk[i] = (__bf16)w[(tap * 32 + s) * 128 + n];
}

__device__ __forceinline__ bf16x8 cvt8(const float* p) {
    const float4 f0 = *(const float4*)p;
    const float4 f1 = *(const float4*)(p + 4);
    bf16x8 v;
    v[0] = (__bf16)f0.x; v[1] = (__bf16)f0.y;
    v[2] = (__bf16)f0.z; v[3] = (__bf16)f0.w;
    v[4] = (__bf16)f1.x; v[5] = (__bf16)f1.y;
    v[6] = (__bf16)f1.z; v[7] = (__bf16)f1.w;
    return v;
}

__global__ __launch_bounds__(512, 4) void clstm_orow(
    const float* __restrict__ x,
    const __bf16* __restrict__ wpk1, const __bf16* __restrict__ wpk2,
    const float* __restrict__ bias1, const float* __restrict__ bias2,
    __bf16* __restrict__ h1buf,       // 4 planes, t%4
    __bf16* __restrict__ h2buf,       // 2 parity planes (odd t)
    float* __restrict__ c1,           // 2 parity planes (odd t)
    float* __restrict__ c2,
    float* __restrict__ out, int j)
{
    __shared__ __bf16 tXA[5 * 66 * TS];      // step-A input src rows y0-2..y0+2
    __shared__ __bf16 tRA[5 * 66 * TS];      // step-A recurrent src (h@T0-1)
    __shared__ __bf16 tXB[3 * 66 * TS];      // step-B input src rows y0-1..y0+1
    __shared__ __bf16 tHA[3 * 66 * TS + 4];  // h@T0 rows y0-1..y0+1 (zero borders)
    __shared__ float  cpass[64 * 32];        // c@T0, own row

    const int blk = blockIdx.x;
    const int u = (blk & 7) * 64 + (blk >> 3);   // XCD-contiguous units
    const int layer = u & 1;
    if (layer ? (j < 1) : (j > 7)) return;
    const int ru = u >> 1;                       // 0..255
    const int b = ru >> 6, y0 = ru & 63;
    const int T0 = layer ? (2 * j - 2) : (2 * j);

    const int tid = threadIdx.x;
    const int wid = tid >> 6, L = tid & 63;
    const int c = L & 15, q = L >> 4, q8 = q * 8;

    const bf16x8* wpkv = (const bf16x8*)(layer ? wpk2 : wpk1);
    const float* bias = layer ? bias2 : bias1;
    float bv[2][4];
    #pragma unroll
    for (int fh2 = 0; fh2 < 2; ++fh2)
        #pragma unroll
        for (int g = 0; g < 4; ++g)
            bv[fh2][g] = bias[g * 32 + fh2 * 16 + c];

    float* cl = layer ? c2 : c1;
    const float*  xA  = x + (size_t)(b * 16 + T0) * 131072;
    const float*  xB  = xA + 131072;
    const __bf16* h1A = h1buf + (size_t)(T0 & 3) * PLANE;
    const __bf16* h1B = h1buf + (size_t)((T0 + 1) & 3) * PLANE;
    const __bf16* hRA = layer ? (h2buf + (size_t)(((T0 - 1) >> 1) & 1) * PLANE)
                              : (h1buf + (size_t)((T0 - 1) & 3) * PLANE);

    // ================= P1: stage tXA (+tRA), tXB; zero tHA ==================
    const int n1 = T0 ? 2640 : 1320;
    for (int i = tid; i < n1; i += 512) {
        const int tile = (i >= 1320);
        const int r2 = i - tile * 1320;
        const int g = r2 & 3;
        const int rc = r2 >> 2;
        const int cc = rc % 66;
        const int rw = rc / 66;
        const int yy = y0 - 2 + rw;
        const int xc = cc - 1;
        bf16x8 v = {};
        if ((unsigned)yy < 64u && (unsigned)xc < 64u) {
            if (!layer && !tile) {
                v = cvt8(xA + ((size_t)yy * 64 + xc) * 32 + g * 8);
            } else {
                const __bf16* s = tile ? hRA : h1A;
                v = *(const bf16x8*)(s + (((size_t)(b * 64 + yy)) * 64 + xc) * 32 + g * 8);
            }
        }
        *(bf16x8*)((tile ? tRA : tXA) + (rw * 66 + cc) * TS + g * 8) = v;
    }
    for (int i = tid; i < 792; i += 512) {
        const int g = i & 3;
        const int rc = i >> 2;
        const int cc = rc % 66;
        const int rw = rc / 66;
        const int yy = y0 - 1 + rw;
        const int xc = cc - 1;
        bf16x8 v = {};
        if ((unsigned)yy < 64u && (unsigned)xc < 64u) {
            if (!layer) v = cvt8(xB + ((size_t)yy * 64 + xc) * 32 + g * 8);
            else        v = *(const bf16x8*)(h1B + (((size_t)(b * 64 + yy)) * 64 + xc) * 32 + g * 8);
        }
        *(bf16x8*)(tXB + (rw * 66 + cc) * TS + g * 8) = v;
    }
    for (int i = tid; i < 842; i += 512)          // 842*8 = 6736 >= 3*66*34+4
        *(bf16x8*)(tHA + i * 8) = (bf16x8){};
    __syncthreads();

    // ================= P2 ====================================================
    f32x4 accB[2][2][4];   // stepB acc (waves 6,7), lives across barrier

    if (wid < 6) {
        // ---- step A unit: (row = wid>>1 in 0..2, mp = wid&1), both fh ----
        const int row = wid >> 1, mp = wid & 1;
        const int yy = y0 - 1 + row;
        if ((unsigned)yy < 64u) {
            f32x4 acc[2][2][4];
            #pragma unroll
            for (int fh2 = 0; fh2 < 2; ++fh2)
                #pragma unroll
                for (int m2 = 0; m2 < 2; ++m2)
                    #pragma unroll
                    for (int g = 0; g < 4; ++g)
                        acc[fh2][m2][g] = (f32x4){bv[fh2][g], bv[fh2][g], bv[fh2][g], bv[fh2][g]};

            #pragma unroll
            for (int tap = 0; tap < 9; ++tap) {
                const int dyk = tap / 3, dxk = tap - dyk * 3;
                const int base = ((row + dyk) * 66 + mp * 32 + c + dxk) * TS + q8;
                const bf16x8 a0 = *(const bf16x8*)(tXA + base);
                const bf16x8 a1 = *(const bf16x8*)(tXA + base + 16 * TS);
                #pragma unroll
                for (int fh2 = 0; fh2 < 2; ++fh2) {
                    const bf16x8* wl = wpkv + (size_t)((tap * 2) * 8 + fh2 * 4) * 64 + L;
                    #pragma unroll
                    for (int g = 0; g < 4; ++g) {
                        const bf16x8 wb = wl[g * 64];
                        acc[fh2][0][g] = __builtin_amdgcn_mfma_f32_16x16x32_bf16(a0, wb, acc[fh2][0][g], 0, 0, 0);
                        acc[fh2][1][g] = __builtin_amdgcn_mfma_f32_16x16x32_bf16(a1, wb, acc[fh2][1][g], 0, 0, 0);
                    }
                }
                if (T0 > 0) {
                    const bf16x8 h0 = *(const bf16x8*)(tRA + base);
                    const bf16x8 h1v = *(const bf16x8*)(tRA + base + 16 * TS);
                    #pragma unroll
                    for (int fh2 = 0; fh2 < 2; ++fh2) {
                        const bf16x8* wl = wpkv + (size_t)((tap * 2 + 1) * 8 + fh2 * 4) * 64 + L;
                        #pragma unroll
                        for (int g = 0; g < 4; ++g) {
                            const bf16x8 wb = wl[g * 64];
                            acc[fh2][0][g] = __builtin_amdgcn_mfma_f32_16x16x32_bf16(h0, wb, acc[fh2][0][g], 0, 0, 0);
                            acc[fh2][1][g] = __builtin_amdgcn_mfma_f32_16x16x32_bf16(h1v, wb, acc[fh2][1][g], 0, 0, 0);
                        }
                    }
                }
            }

            // ---- epilogue A: write tHA (LDS); own row -> cpass + global h ----
            const float* crd = cl + (size_t)((j - 1) & 1) * PLANE;
            const size_t rowA = (size_t)(b * 64 + yy) * 2048;
            #pragma unroll
            for (int fh2 = 0; fh2 < 2; ++fh2) {
                const int f2 = fh2 * 16 + c;
                #pragma unroll
                for (int m2 = 0; m2 < 2; ++m2) {
                    #pragma unroll
                    for (int r = 0; r < 4; ++r) {
                        const int px = mp * 32 + m2 * 16 + q * 4 + r;
                        const float ig = fsigmoid(acc[fh2][m2][0][r]);
                        const float fg = fsigmoid(acc[fh2][m2][1][r]);
                        const float gg = ftanh(acc[fh2][m2][2][r]);
                        const float og = fsigmoid(acc[fh2][m2][3][r]);
                        const float cold = T0 ? crd[rowA + (size_t)px * 32 + f2] : 0.0f;
                        const float cn = (T0 ? fg * cold : 0.0f) + ig * gg;
                        const float hv = og * ftanh(cn);
                        tHA[(row * 66 + px + 1) * TS + f2] = (__bf16)hv;
                        if (row == 1) {
                            cpass[px * 32 + f2] = cn;
                            if (layer)
                                out[((size_t)(b * 16 + T0) * 4096 + (size_t)y0 * 64 + px) * 32 + f2] = hv;
                            else
                                h1buf[(size_t)(T0 & 3) * PLANE + rowA + (size_t)px * 32 + f2] = (__bf16)hv;
                        }
                    }
                }
            }
        }
    } else {
        // ---- step B x-side (independent of step A): unit mp = wid-6 ----
        const int mp = wid - 6;
        #pragma unroll
        for (int fh2 = 0; fh2 < 2; ++fh2)
            #pragma unroll
            for (int m2 = 0; m2 < 2; ++m2)
                #pragma unroll
                for (int g = 0; g < 4; ++g)
                    accB[fh2][m2][g] = (f32x4){bv[fh2][g], bv[fh2][g], bv[fh2][g], bv[fh2][g]};

        #pragma unroll
        for (int tap = 0; tap < 9; ++tap) {
            const int dyk = tap / 3, dxk = tap - dyk * 3;
            const int base = (dyk * 66 + mp * 32 + c + dxk) * TS + q8;
            const bf16x8 a0 = *(const bf16x8*)(tXB + base);
            const bf16x8 a1 = *(const bf16x8*)(tXB + base + 16 * TS);
            #pragma unroll
            for (int fh2 = 0; fh2 < 2; ++fh2) {
                const bf16x8* wl = wpkv + (size_t)((tap * 2) * 8 + fh2 * 4) * 64 + L;
                #pragma unroll
                for (int g = 0; g < 4; ++g) {
                    const bf16x8 wb = wl[g * 64];
                    accB[fh2][0][g] = __builtin_amdgcn_mfma_f32_16x16x32_bf16(a0, wb, accB[fh2][0][g], 0, 0, 0);
                    accB[fh2][1][g] = __builtin_amdgcn_mfma_f32_16x16x32_bf16(a1, wb, accB[fh2][1][g], 0, 0, 0);
                }
            }
        }
    }
    __syncthreads();

    // ================= P3: step B h-side + epilogue B (waves 6,7) ===========
    if (wid >= 6) {
        const int mp = wid - 6;
        #pragma unroll
        for (int tap = 0; tap < 9; ++tap) {
            const int dyk = tap / 3, dxk = tap - dyk * 3;
            const int base = (dyk * 66 + mp * 32 + c + dxk) * TS + q8;
            const bf16x8 h0 = *(const bf16x8*)(tHA + base);
            const bf16x8 h1v = *(const bf16x8*)(tHA + base + 16 * TS);
            #pragma unroll
            for (int fh2 = 0; fh2 < 2; ++fh2) {
                const bf16x8* wl = wpkv + (size_t)((tap * 2 + 1) * 8 + fh2 * 4) * 64 + L;
                #pragma unroll
                for (int g = 0; g < 4; ++g) {
                    const bf16x8 wb = wl[g * 64];
                    accB[fh2][0][g] = __builtin_amdgcn_mfma_f32_16x16x32_bf16(h0, wb, accB[fh2][0][g], 0, 0, 0);
                    accB[fh2][1][g] = __builtin_amdgcn_mfma_f32_16x16x32_bf16(h1v, wb, accB[fh2][1][g], 0, 0, 0);
                }
            }
        }
        float* cwr = cl + (size_t)(j & 1) * PLANE;
        __bf16* h2w = h2buf + (size_t)(((T0 + 1) >> 1) & 1) * PLANE;
        const size_t rowB = (size_t)(b * 64 + y0) * 2048;
        #pragma unroll
        for (int fh2 = 0; fh2 < 2; ++fh2) {
            const int f2 = fh2 * 16 + c;
            #pragma unroll
            for (int m2 = 0; m2 < 2; ++m2) {
                #pragma unroll
                for (int r = 0; r < 4; ++r) {
                    const int px = mp * 32 + m2 * 16 + q * 4 + r;
                    const float ig = fsigmoid(accB[fh2][m2][0][r]);
                    const float fg = fsigmoid(accB[fh2][m2][1][r]);
                    const float gg = ftanh(accB[fh2][m2][2][r]);
                    const float og = fsigmoid(accB[fh2][m2][3][r]);
                    const float cold = cpass[px * 32 + f2];
                    const float cn = fg * cold + ig * gg;
                    const float hv = og * ftanh(cn);
                    cwr[rowB + (size_t)px * 32 + f2] = cn;
                    if (layer) {
                        out[((size_t)(b * 16 + T0 + 1) * 4096 + (size_t)y0 * 64 + px) * 32 + f2] = hv;
                        h2w[rowB + (size_t)px * 32 + f2] = (__bf16)hv;
                    } else {
                        h1buf[(size_t)((T0 + 1) & 3) * PLANE + rowB + (size_t)px * 32 + f2] = (__bf16)hv;
                    }
                }
            }
        }
    }
}

extern "C" void kernel_launch(void* const* d_in, const int* in_sizes, int n_in,
                              void* d_out, int out_size, void* d_ws, size_t ws_size,
                              hipStream_t stream)
{
    const float* x   = (const float*)d_in[0];
    const float* k1  = (const float*)d_in[1];
    const float* rk1 = (const float*)d_in[2];
    const float* b1  = (const float*)d_in[3];
    const float* k2  = (const float*)d_in[4];
    const float* rk2 = (const float*)d_in[5];
    const float* b2  = (const float*)d_in[6];
    float* out = (float*)d_out;

    __bf16* wpk1  = (__bf16*)d_ws;
    __bf16* wpk2  = wpk1 + WPK_ELEMS;
    __bf16* h1buf = wpk2 + WPK_ELEMS;             // 4 planes bf16
    __bf16* h2buf = h1buf + 4 * (size_t)PLANE;    // 2 planes bf16
    float*  c1    = (float*)(h2buf + 2 * (size_t)PLANE);  // 2 planes fp32
    float*  c2    = c1 + 2 * (size_t)PLANE;

    pack_weights<<<(2 * WPK_ELEMS + 255) / 256, 256, 0, stream>>>(k1, rk1, k2, rk2, wpk1);

    for (int j = 0; j <= 8; ++j) {
        clstm_orow<<<512, 512, 0, stream>>>(
            x, wpk1, wpk2, b1, b2, h1buf, h2buf, c1, c2, out, j);
    }
}

// Round 15
// 245.256 us; speedup vs baseline: 1.4835x; 1.4057x over previous
//
#include <hip/hip_runtime.h>

// ConvLSTM2D x2, 2-step temporal blocking, 9 launches (R12 schedule/planes).
// 256 blocks x 1024 thr; block = 2 own rows. Wave repartition for B-reuse:
//   waves 0-7  : step-A units (wr 0..3 x fh), M=64 (full row), N=64.
//                16 MFMAs share each 4-fragment B load (2x the M-reuse of R12).
//   waves 8-11 : step-B units (o 0..1 x fh), M=64: x-side in P2 (concurrent
//                with step A), h-side in P3 from tHA. acc lives across barrier.
//   waves 12-15: staging only.
// Operand traffic ~2.5 -> ~1.7 MB/block (the measured ~26us/launch is operand
// bandwidth + launch overhead; L2 vs LDS proven neutral in R13).

typedef __bf16 bf16x8 __attribute__((ext_vector_type(8)));
typedef float f32x4 __attribute__((ext_vector_type(4)));

#define WPK_ELEMS 73728   // per layer: 18 kchunks * 8 ntiles * 64 lanes * 8
#define PLANE 524288      // 4*64*64*32 elems per plane

__device__ __forceinline__ float fsigmoid(float z) {
    return 1.0f / (1.0f + __expf(-z));
}
__device__ __forceinline__ float ftanh(float z) {
    z = fminf(15.0f, fmaxf(-15.0f, z));
    float e = __expf(2.0f * z);
    return (e - 1.0f) / (e + 1.0f);
}

__global__ __launch_bounds__(256) void pack_weights(
    const float* __restrict__ wk1, const float* __restrict__ wr1,
    const float* __restrict__ wk2, const float* __restrict__ wr2,
    __bf16* __restrict__ wpk)
{
    int i = blockIdx.x * 256 + threadIdx.x;
    if (i >= 2 * WPK_ELEMS) return;
    int layer = i / WPK_ELEMS;
    int r = i - layer * WPK_ELEMS;
    int j2 = r & 7;
    int L  = (r >> 3) & 63;
    int nt = (r >> 9) & 7;
    int cix = r >> 12;            // tap*2 + src
    int tap = cix >> 1, src = cix & 1;
    int s = ((L >> 4) << 3) + j2;
    int gate = nt & 3;
    int f = ((nt >> 2) << 4) + (L & 15);
    int n = (gate << 5) + f;
    const float* w = layer ? (src ? wr2 : wk2) : (src ? wr1 : wk1);
    wpk[i] = (__bf16)w[(tap * 32 + s) * 128 + n];
}

__device__ __forceinline__ bf16x8 cvt8(const float* p) {
    const float4 f0 = *(const float4*)p;
    const float4 f1 = *(const float4*)(p + 4);
    bf16x8 v;
    v[0] = (__bf16)f0.x; v[1] = (__bf16)f0.y;
    v[2] = (__bf16)f0.z; v[3] = (__bf16)f0.w;
    v[4] = (__bf16)f1.x; v[5] = (__bf16)f1.y;
    v[6] = (__bf16)f1.z; v[7] = (__bf16)f1.w;
    return v;
}

// 16 MFMAs: 4 A-tiles (M=64) x 4 gates, sharing one 4-fragment B load.
#define MFMA16(A0, A1, A2, A3, WP, ACC)                                                   \
    {                                                                                     \
        const bf16x8 w0 = WP[0], w1 = WP[64], w2 = WP[128], w3 = WP[192];                 \
        ACC[0][0] = __builtin_amdgcn_mfma_f32_16x16x32_bf16(A0, w0, ACC[0][0], 0, 0, 0);  \
        ACC[0][1] = __builtin_amdgcn_mfma_f32_16x16x32_bf16(A0, w1, ACC[0][1], 0, 0, 0);  \
        ACC[0][2] = __builtin_amdgcn_mfma_f32_16x16x32_bf16(A0, w2, ACC[0][2], 0, 0, 0);  \
        ACC[0][3] = __builtin_amdgcn_mfma_f32_16x16x32_bf16(A0, w3, ACC[0][3], 0, 0, 0);  \
        ACC[1][0] = __builtin_amdgcn_mfma_f32_16x16x32_bf16(A1, w0, ACC[1][0], 0, 0, 0);  \
        ACC[1][1] = __builtin_amdgcn_mfma_f32_16x16x32_bf16(A1, w1, ACC[1][1], 0, 0, 0);  \
        ACC[1][2] = __builtin_amdgcn_mfma_f32_16x16x32_bf16(A1, w2, ACC[1][2], 0, 0, 0);  \
        ACC[1][3] = __builtin_amdgcn_mfma_f32_16x16x32_bf16(A1, w3, ACC[1][3], 0, 0, 0);  \
        ACC[2][0] = __builtin_amdgcn_mfma_f32_16x16x32_bf16(A2, w0, ACC[2][0], 0, 0, 0);  \
        ACC[2][1] = __builtin_amdgcn_mfma_f32_16x16x32_bf16(A2, w1, ACC[2][1], 0, 0, 0);  \
        ACC[2][2] = __builtin_amdgcn_mfma_f32_16x16x32_bf16(A2, w2, ACC[2][2], 0, 0, 0);  \
        ACC[2][3] = __builtin_amdgcn_mfma_f32_16x16x32_bf16(A2, w3, ACC[2][3], 0, 0, 0);  \
        ACC[3][0] = __builtin_amdgcn_mfma_f32_16x16x32_bf16(A3, w0, ACC[3][0], 0, 0, 0);  \
        ACC[3][1] = __builtin_amdgcn_mfma_f32_16x16x32_bf16(A3, w1, ACC[3][1], 0, 0, 0);  \
        ACC[3][2] = __builtin_amdgcn_mfma_f32_16x16x32_bf16(A3, w2, ACC[3][2], 0, 0, 0);  \
        ACC[3][3] = __builtin_amdgcn_mfma_f32_16x16x32_bf16(A3, w3, ACC[3][3], 0, 0, 0);  \
    }

__global__ __launch_bounds__(1024, 1) void clstm_m64(
    const float* __restrict__ x,
    const __bf16* __restrict__ wpk1, const __bf16* __restrict__ wpk2,
    const float* __restrict__ bias1, const float* __restrict__ bias2,
    __bf16* __restrict__ h1buf,       // 4 planes, t%4
    __bf16* __restrict__ h2buf,       // 2 parity planes (odd t)
    float* __restrict__ c1,           // 2 parity planes (odd t)
    float* __restrict__ c2,
    float* __restrict__ out, int j)
{
    __shared__ __bf16 tXA[6 * 66 * 36];   // step-A input src rows y0-2..y0+3
    __shared__ __bf16 tRA[6 * 66 * 36];   // step-A recurrent src (h@T0-1)
    __shared__ __bf16 tXB[4 * 66 * 36];   // step-B input src rows y0-1..y0+2
    __shared__ __bf16 tHA[4 * 66 * 36];   // h@T0 rows y0-1..y0+2 (zero borders)
    __shared__ float  cpass[2 * 64 * 32]; // c@T0, own rows

    const int blk = blockIdx.x;
    const int k = blk >> 3;
    const int layer = k >> 4;
    if (layer ? (j < 1) : (j > 7)) return;
    const int grp = (blk & 7) * 16 + (k & 15);   // XCD-contiguous rows
    const int T0 = layer ? (2 * j - 2) : (2 * j);
    const int R = grp << 1;
    const int b = R >> 6, y0 = R & 63;

    const int tid = threadIdx.x;
    const int wid = tid >> 6, L = tid & 63;
    const int c = L & 15, q = L >> 4, q8 = q * 8;

    const bf16x8* wpkv = (const bf16x8*)(layer ? wpk2 : wpk1);
    const float* bias = layer ? bias2 : bias1;
    float* cl = layer ? c2 : c1;

    const float*  xA  = x + (size_t)(b * 16 + T0) * 131072;
    const float*  xB  = xA + 131072;
    const __bf16* h1A = h1buf + (size_t)(T0 & 3) * PLANE;
    const __bf16* h1B = h1buf + (size_t)((T0 + 1) & 3) * PLANE;
    const __bf16* hRA = layer ? (h2buf + (size_t)(((T0 - 1) >> 1) & 1) * PLANE)
                              : (h1buf + (size_t)((T0 - 1) & 3) * PLANE);

    // ================= P1: stage tXA (+tRA), tXB; zero tHA ==================
    const int n1 = T0 ? 3168 : 1584;
    for (int i = tid; i < n1; i += 1024) {
        const int tile = (i >= 1584);
        const int r2 = i - tile * 1584;
        const int g = r2 & 3;
        const int rc = r2 >> 2;
        const int cc = rc % 66;
        const int row = rc / 66;
        const int yy = y0 - 2 + row;
        const int xc = cc - 1;
        bf16x8 v = {};
        if ((unsigned)yy < 64u && (unsigned)xc < 64u) {
            if (!layer && !tile) {
                v = cvt8(xA + ((size_t)yy * 64 + xc) * 32 + g * 8);
            } else {
                const __bf16* s = tile ? hRA : h1A;
                v = *(const bf16x8*)(s + (((size_t)(b * 64 + yy)) * 64 + xc) * 32 + g * 8);
            }
        }
        *(bf16x8*)((tile ? tRA : tXA) + (row * 66 + cc) * 36 + g * 8) = v;
    }
    for (int i = tid; i < 1056; i += 1024) {
        const int g = i & 3;
        const int rc = i >> 2;
        const int cc = rc % 66;
        const int row = rc / 66;
        const int yy = y0 - 1 + row;
        const int xc = cc - 1;
        bf16x8 v = {};
        if ((unsigned)yy < 64u && (unsigned)xc < 64u) {
            if (!layer) v = cvt8(xB + ((size_t)yy * 64 + xc) * 32 + g * 8);
            else        v = *(const bf16x8*)(h1B + (((size_t)(b * 64 + yy)) * 64 + xc) * 32 + g * 8);
        }
        *(bf16x8*)(tXB + (row * 66 + cc) * 36 + g * 8) = v;
    }
    for (int i = tid; i < 1188; i += 1024)
        *(bf16x8*)(tHA + i * 8) = (bf16x8){};
    __syncthreads();

    // ================= P2 ====================================================
    f32x4 accB[4][4];   // step-B acc (waves 8-11), lives across the barrier

    if (wid < 8) {
        // ---- step A unit: (wr = wid>>1 in 0..3, fh = wid&1), M=64, N=64 ----
        const int wr = wid >> 1, fh = wid & 1;
        const int f = fh * 16 + c;
        const int ra = y0 - 1 + wr;
        const bool rv = ((unsigned)ra < 64u);
        if (rv) {
            float bv[4];
            #pragma unroll
            for (int g = 0; g < 4; ++g) bv[g] = bias[g * 32 + f];

            f32x4 acc[4][4];
            #pragma unroll
            for (int m = 0; m < 4; ++m)
                #pragma unroll
                for (int g = 0; g < 4; ++g)
                    acc[m][g] = (f32x4){bv[g], bv[g], bv[g], bv[g]};

            #pragma unroll
            for (int tap = 0; tap < 9; ++tap) {
                const int dyk = tap / 3, dxk = tap - dyk * 3;
                const int lb = ((wr + dyk) * 66 + c + dxk) * 36 + q8;
                {
                    const bf16x8 a0 = *(const bf16x8*)(tXA + lb);
                    const bf16x8 a1 = *(const bf16x8*)(tXA + lb + 16 * 36);
                    const bf16x8 a2 = *(const bf16x8*)(tXA + lb + 32 * 36);
                    const bf16x8 a3 = *(const bf16x8*)(tXA + lb + 48 * 36);
                    const bf16x8* wp = wpkv + (size_t)((tap * 2) * 8 + fh * 4) * 64 + L;
                    MFMA16(a0, a1, a2, a3, wp, acc);
                }
                if (T0 > 0) {
                    const bf16x8 h0 = *(const bf16x8*)(tRA + lb);
                    const bf16x8 h1v = *(const bf16x8*)(tRA + lb + 16 * 36);
                    const bf16x8 h2v = *(const bf16x8*)(tRA + lb + 32 * 36);
                    const bf16x8 h3v = *(const bf16x8*)(tRA + lb + 48 * 36);
                    const bf16x8* wp = wpkv + (size_t)((tap * 2 + 1) * 8 + fh * 4) * 64 + L;
                    MFMA16(h0, h1v, h2v, h3v, wp, acc);
                }
            }

            // ---- epilogue A ----
            const bool own = (wr == 1 || wr == 2);
            const float* crd = cl + (size_t)((j - 1) & 1) * PLANE;
            const size_t rowA = (size_t)(b * 64 + ra) * 2048;
            #pragma unroll
            for (int m = 0; m < 4; ++m) {
                #pragma unroll
                for (int r = 0; r < 4; ++r) {
                    const int px = m * 16 + q * 4 + r;
                    const float ig = fsigmoid(acc[m][0][r]);
                    const float fg = fsigmoid(acc[m][1][r]);
                    const float gg = ftanh(acc[m][2][r]);
                    const float og = fsigmoid(acc[m][3][r]);
                    const float cold = T0 ? crd[rowA + (size_t)px * 32 + f] : 0.0f;
                    const float cn = (T0 ? fg * cold : 0.0f) + ig * gg;
                    const float hv = og * ftanh(cn);
                    tHA[(wr * 66 + px + 1) * 36 + f] = (__bf16)hv;
                    if (own) {
                        cpass[(wr - 1) * 2048 + px * 32 + f] = cn;
                        if (layer)
                            out[((size_t)(b * 16 + T0) * 4096 + (size_t)ra * 64 + px) * 32 + f] = hv;
                        else
                            h1buf[(size_t)(T0 & 3) * PLANE + rowA + (size_t)px * 32 + f] = (__bf16)hv;
                    }
                }
            }
        }
    } else if (wid < 12) {
        // ---- step B x-side: unit (o = (wid-8)>>1, fh = (wid-8)&1), M=64 ----
        const int u = wid - 8;
        const int o = u >> 1, fh = u & 1;
        const int f = fh * 16 + c;
        float bv[4];
        #pragma unroll
        for (int g = 0; g < 4; ++g) bv[g] = bias[g * 32 + f];
        #pragma unroll
        for (int m = 0; m < 4; ++m)
            #pragma unroll
            for (int g = 0; g < 4; ++g)
                accB[m][g] = (f32x4){bv[g], bv[g], bv[g], bv[g]};

        #pragma unroll
        for (int tap = 0; tap < 9; ++tap) {
            const int dyk = tap / 3, dxk = tap - dyk * 3;
            const int lb = ((o + dyk) * 66 + c + dxk) * 36 + q8;
            const bf16x8 a0 = *(const bf16x8*)(tXB + lb);
            const bf16x8 a1 = *(const bf16x8*)(tXB + lb + 16 * 36);
            const bf16x8 a2 = *(const bf16x8*)(tXB + lb + 32 * 36);
            const bf16x8 a3 = *(const bf16x8*)(tXB + lb + 48 * 36);
            const bf16x8* wp = wpkv + (size_t)((tap * 2) * 8 + fh * 4) * 64 + L;
            MFMA16(a0, a1, a2, a3, wp, accB);
        }
    }
    __syncthreads();

    // ================= P3: step B h-side + epilogue B (waves 8-11) ==========
    if (wid >= 8 && wid < 12) {
        const int u = wid - 8;
        const int o = u >> 1, fh = u & 1;
        const int f = fh * 16 + c;
        #pragma unroll
        for (int tap = 0; tap < 9; ++tap) {
            const int dyk = tap / 3, dxk = tap - dyk * 3;
            const int lb = ((o + dyk) * 66 + c + dxk) * 36 + q8;
            const bf16x8 h0 = *(const bf16x8*)(tHA + lb);
            const bf16x8 h1v = *(const bf16x8*)(tHA + lb + 16 * 36);
            const bf16x8 h2v = *(const bf16x8*)(tHA + lb + 32 * 36);
            const bf16x8 h3v = *(const bf16x8*)(tHA + lb + 48 * 36);
            const bf16x8* wp = wpkv + (size_t)((tap * 2 + 1) * 8 + fh * 4) * 64 + L;
            MFMA16(h0, h1v, h2v, h3v, wp, accB);
        }
        const int rb = y0 + o;
        float* cwr = cl + (size_t)(j & 1) * PLANE;
        __bf16* h2w = h2buf + (size_t)(((T0 + 1) >> 1) & 1) * PLANE;
        const size_t rowB = (size_t)(b * 64 + rb) * 2048;
        #pragma unroll
        for (int m = 0; m < 4; ++m) {
            #pragma unroll
            for (int r = 0; r < 4; ++r) {
                const int px = m * 16 + q * 4 + r;
                const float ig = fsigmoid(accB[m][0][r]);
                const float fg = fsigmoid(accB[m][1][r]);
                const float gg = ftanh(accB[m][2][r]);
                const float og = fsigmoid(accB[m][3][r]);
                const float cold = cpass[o * 2048 + px * 32 + f];
                const float cn = fg * cold + ig * gg;
                const float hv = og * ftanh(cn);
                cwr[rowB + (size_t)px * 32 + f] = cn;
                if (layer) {
                    out[((size_t)(b * 16 + T0 + 1) * 4096 + (size_t)rb * 64 + px) * 32 + f] = hv;
                    h2w[rowB + (size_t)px * 32 + f] = (__bf16)hv;
                } else {
                    h1buf[(size_t)((T0 + 1) & 3) * PLANE + rowB + (size_t)px * 32 + f] = (__bf16)hv;
                }
            }
        }
    }
}

extern "C" void kernel_launch(void* const* d_in, const int* in_sizes, int n_in,
                              void* d_out, int out_size, void* d_ws, size_t ws_size,
                              hipStream_t stream)
{
    const float* x   = (const float*)d_in[0];
    const float* k1  = (const float*)d_in[1];
    const float* rk1 = (const float*)d_in[2];
    const float* b1  = (const float*)d_in[3];
    const float* k2  = (const float*)d_in[4];
    const float* rk2 = (const float*)d_in[5];
    const float* b2  = (const float*)d_in[6];
    float* out = (float*)d_out;

    __bf16* wpk1  = (__bf16*)d_ws;
    __bf16* wpk2  = wpk1 + WPK_ELEMS;
    __bf16* h1buf = wpk2 + WPK_ELEMS;             // 4 planes bf16
    __bf16* h2buf = h1buf + 4 * (size_t)PLANE;    // 2 planes bf16
    float*  c1    = (float*)(h2buf + 2 * (size_t)PLANE);  // 2 planes fp32
    float*  c2    = c1 + 2 * (size_t)PLANE;

    pack_weights<<<(2 * WPK_ELEMS + 255) / 256, 256, 0, stream>>>(k1, rk1, k2, rk2, wpk1);

    for (int j = 0; j <= 8; ++j) {
        clstm_m64<<<256, 1024, 0, stream>>>(
            x, wpk1, wpk2, b1, b2, h1buf, h2buf, c1, c2, out, j);
    }
}